// Round 3
// baseline (320.141 us; speedup 1.0000x reference)
//
#include <hip/hip_runtime.h>

#define HWSZ 4096
#define NTRI 136
#define NSTAT 152
#define NST2 304   // two partial rows per instance
#define NINST 512
#define GCNT 16
#define EPSW 1e-5f

// global stat index of covariance pair (a<=b): s1 occupies [0,16)
#define TRI(a, b) (16 + 15 * (a) - ((a) * ((a)-1)) / 2 + (b))

typedef float v2f __attribute__((ext_vector_type(2)));
typedef float v4f __attribute__((ext_vector_type(4)));

// ---------------------------------------------------------------------------
// K1: per-instance stats, PAIR-COOPERATIVE channel split + position split.
//   grid = 1024: block (2b+ph) handles instance b, position half ph.
//   Within a block, thread pair (2p, 2p+1) covers position-pair p:
//     even lane loads channels 0-7, odd lane loads channels 8-15,
//     partner values via __shfl_xor(.,1)  ->  EVERY x element loaded ONCE
//     (round-2 triangle split paid 1.75x traffic; occupancy gain was exactly
//     cancelled -> 87 us both ways. This keeps the grid/occupancy, drops
//     traffic to 1x = 128 MB logical).
//   Per-thread accumulators: 8 s1 + 36 within-half tri + 32 cross = 76.
//
// REGISTER CAP HISTORY (do not regress):
//  - (256,4): 128-reg unified cap spills ~120 live regs (WRITE_SIZE 87 MB).
//  - (256,3): cap ~168, ~76 accums + ~60 transient fits. KEEP (256,3).
//  Spill tripwire: WRITE_SIZE for this dispatch must stay ~640 KB.
//
// CRITICAL register discipline:
//  - position loop = "#pragma unroll 1"; EVERY loop indexing accumulators =
//    full unroll (dynamic indexing demotes the array to scratch).
//  - cross products use cndmask-selected lo/hi (24 selects/iter), NOT a
//    divergent if(par) block (that would serialize both 64-FMA paths).
//
// Parity-aware reduction: shuffle offsets 32,16,8,4,2 preserve lane parity;
// after them lane 0 holds the even-lane (ch 0-7 owner) sum, lane 1 the odd.
// Mapping (verified against TRI layout of the fused kernel):
//   even: s1[c]->c        sw(c,d)->TRI(c,d)       sx(c,e)->TRI(c, 8+e)
//   odd:  s1[c]->8+c      sw(c,d)->TRI(8+c,8+d)   sx(c,e)->TRI(c,12+e)
//     (odd cross value = w[c]*v[4+e] = ch c * ch 12+e)
// ---------------------------------------------------------------------------
__global__ __launch_bounds__(256, 3) void k_inst_stats(const float* __restrict__ x,
                                                       float* __restrict__ partials) {
  const int bb = blockIdx.x;
  const int b = bb >> 1;      // instance
  const int ph = bb & 1;      // position half
  const int t = threadIdx.x;
  const int lane = t & 63;
  const int wv = t >> 6;
  const int par = t & 1;      // channel-half parity
  const int p = t >> 1;       // position-pair slot 0..127
  const v2f* xb = (const v2f*)x + (size_t)b * 16 * 2048 + (size_t)par * 8 * 2048;
  const int f0 = ph * 1024 + p;

  __shared__ float red[4 * NSTAT];

  float s1[8];
  float sw[36];
  float sx[32];
#pragma unroll
  for (int i = 0; i < 8; ++i) s1[i] = 0.f;
#pragma unroll
  for (int i = 0; i < 36; ++i) sw[i] = 0.f;
#pragma unroll
  for (int i = 0; i < 32; ++i) sx[i] = 0.f;

#pragma unroll 1
  for (int k = 0; k < 8; ++k) {
    const int f = f0 + k * 128;
    v2f v[8];
#pragma unroll
    for (int d = 0; d < 8; ++d) v[d] = xb[d * 2048 + f];
    // partner exchange (lane^1): even gets ch 8-15, odd gets ch 0-7
    v2f w[8];
#pragma unroll
    for (int d = 0; d < 8; ++d) {
      w[d].x = __shfl_xor(v[d].x, 1);
      w[d].y = __shfl_xor(v[d].y, 1);
    }
    // own-channel stats (parity-uniform on v)
#pragma unroll
    for (int c = 0; c < 8; ++c) s1[c] += v[c].x + v[c].y;
    {
      int idx = 0;
#pragma unroll
      for (int c = 0; c < 8; ++c) {
#pragma unroll
        for (int d = c; d < 8; ++d) {
          sw[idx] += v[c].x * v[d].x + v[c].y * v[d].y;
          ++idx;
        }
      }
    }
    // cross: canonical lo (ch 0-7) / hi (4 assigned high channels)
    v2f lo[8], hi[4];
#pragma unroll
    for (int c = 0; c < 8; ++c) lo[c] = par ? w[c] : v[c];
#pragma unroll
    for (int e = 0; e < 4; ++e) hi[e] = par ? v[4 + e] : w[e];
#pragma unroll
    for (int c = 0; c < 8; ++c) {
#pragma unroll
      for (int e = 0; e < 4; ++e) {
        sx[c * 4 + e] += lo[c].x * hi[e].x + lo[c].y * hi[e].y;
      }
    }
  }

  // ---- parity-preserving wave reduction + mapped LDS writeout ----
#pragma unroll
  for (int c = 0; c < 8; ++c) {
    float v = s1[c];
#pragma unroll
    for (int off = 32; off > 1; off >>= 1) v += __shfl_down(v, off);
    if (lane == 0) red[wv * NSTAT + c] = v;
    if (lane == 1) red[wv * NSTAT + 8 + c] = v;
  }
  {
    int idx = 0;
#pragma unroll
    for (int c = 0; c < 8; ++c) {
#pragma unroll
      for (int d = c; d < 8; ++d) {
        float v = sw[idx];
#pragma unroll
        for (int off = 32; off > 1; off >>= 1) v += __shfl_down(v, off);
        if (lane == 0) red[wv * NSTAT + TRI(c, d)] = v;
        if (lane == 1) red[wv * NSTAT + TRI(8 + c, 8 + d)] = v;
        ++idx;
      }
    }
  }
#pragma unroll
  for (int c = 0; c < 8; ++c) {
#pragma unroll
    for (int e = 0; e < 4; ++e) {
      float v = sx[c * 4 + e];
#pragma unroll
      for (int off = 32; off > 1; off >>= 1) v += __shfl_down(v, off);
      if (lane == 0) red[wv * NSTAT + TRI(c, 8 + e)] = v;
      if (lane == 1) red[wv * NSTAT + TRI(c, 12 + e)] = v;
    }
  }
  __syncthreads();
  if (t < NSTAT) {
    partials[(size_t)bb * NSTAT + t] =
        red[t] + red[NSTAT + t] + red[2 * NSTAT + t] + red[3 * NSTAT + t];
  }
}

// ---------------------------------------------------------------------------
// K3: per-instance mixing + Newton-Schulz, with group stats fused in.
// Reads TWO partial rows per instance (position halves) and sums them.
// One block (256 thr) per instance; thread t owns element (row=t>>4, col=t&15).
// Outputs folded affine transform: y = W' x + o.
// ---------------------------------------------------------------------------
__global__ __launch_bounds__(256) void k_newton(const float* __restrict__ partials,
                                                const float* __restrict__ swm,
                                                const float* __restrict__ swv,
                                                const float* __restrict__ weight,
                                                const float* __restrict__ bias,
                                                float* __restrict__ apply_wm,
                                                float* __restrict__ apply_ofs) {
  const int b = blockIdx.x;
  const int g = b & 15;
  const int t = threadIdx.x;
  const int r = t >> 4;
  const int c = t & 15;

  __shared__ float P[256], Qm[256], Rm[256], CN[256], Wl[256];
  __shared__ float Mm[16], Mi[16], Mb[16];
  __shared__ float Gs[NSTAT];
  __shared__ float Is[NSTAT];

  // per-instance stats (sum of the two position-half partials)
  if (t < NSTAT) {
    const float* row = partials + (size_t)b * NST2;
    Is[t] = row[t] + row[NSTAT + t];
    // fused K2: group sums over the 32 instances (64 partial rows)
    float s = 0.f;
#pragma unroll 8
    for (int n = 0; n < 32; ++n) {
      const float* rn = partials + (size_t)(n * GCNT + g) * NST2;
      s += rn[t] + rn[NSTAT + t];
    }
    Gs[t] = s;
  }

  float a0 = swm[0], a1 = swm[1];
  float mx = fmaxf(a0, a1);
  float e0 = expf(a0 - mx), e1 = expf(a1 - mx);
  const float mw0 = e0 / (e0 + e1), mw1 = e1 / (e0 + e1);
  a0 = swv[0]; a1 = swv[1];
  mx = fmaxf(a0, a1);
  e0 = expf(a0 - mx); e1 = expf(a1 - mx);
  const float vw0 = e0 / (e0 + e1), vw1 = e1 / (e0 + e1);

  const float inv_hw = 1.0f / (float)HWSZ;
  const float inv_nhw = 1.0f / (32.0f * (float)HWSZ);

  __syncthreads();

  if (t < 16) {
    const float mi = Is[t] * inv_hw;
    const float mb = Gs[t] * inv_nhw;
    Mi[t] = mi;
    Mb[t] = mb;
    Mm[t] = mw0 * mb + mw1 * mi;
  }
  __syncthreads();

  const int cmin = (r < c) ? r : c;
  const int cmax = (r < c) ? c : r;
  const int tri = 15 * cmin - (cmin * (cmin - 1)) / 2 + cmax + 16;
  const float cin = Is[tri] * inv_hw - Mi[r] * Mi[c];
  const float cbn = Gs[tri] * inv_nhw - Mb[r] * Mb[c];
  float cov = vw0 * cbn + vw1 * cin + ((r == c) ? EPSW : 0.0f);

  Qm[t] = cov;
  __syncthreads();
  float trace = 0.f;
#pragma unroll
  for (int i = 0; i < 16; ++i) trace += Qm[i * 16 + i];
  const float rTr = 1.0f / trace;

  CN[t] = cov * rTr;
  P[t] = (r == c) ? 1.0f : 0.0f;
  __syncthreads();

  for (int it = 0; it < 5; ++it) {
    float q = 0.f;
#pragma unroll
    for (int k = 0; k < 16; ++k) q += P[r * 16 + k] * P[k * 16 + c];
    Qm[t] = q;
    __syncthreads();
    float rr = 0.f;
#pragma unroll
    for (int k = 0; k < 16; ++k) rr += Qm[r * 16 + k] * P[k * 16 + c];
    Rm[t] = rr;
    __syncthreads();
    float tt = 0.f;
#pragma unroll
    for (int k = 0; k < 16; ++k) tt += Rm[r * 16 + k] * CN[k * 16 + c];
    const float np = 1.5f * P[t] - 0.5f * tt;
    __syncthreads();
    P[t] = np;
    __syncthreads();
  }

  const float sr = sqrtf(rTr);
  const float wel = P[t] * sr * weight[g * 16 + r];
  Wl[t] = wel;
  apply_wm[(size_t)b * 256 + t] = wel;
  __syncthreads();
  if (t < 16) {
    float acc = 0.f;
#pragma unroll
    for (int d = 0; d < 16; ++d) acc += Wl[t * 16 + d] * Mm[d];
    apply_ofs[(size_t)b * 16 + t] = bias[g * 16 + t] - acc;
  }
}

// ---------------------------------------------------------------------------
// K4: apply y = W' x + o. 4 blocks per instance (2048 blocks); each thread
// owns ONE float4 column (all 16 channels). ~100 live VGPRs -> 4 waves/EU.
// ---------------------------------------------------------------------------
__global__ __launch_bounds__(256, 4) void k_apply(const float* __restrict__ x,
                                                  const float* __restrict__ apply_wm,
                                                  const float* __restrict__ apply_ofs,
                                                  float* __restrict__ y) {
  const int bb = blockIdx.x;
  const int b = bb >> 2;      // instance
  const int chunk = bb & 3;   // position chunk
  const int t = threadIdx.x;

  __shared__ float Wl[256];
  __shared__ float Ol[16];
  Wl[t] = apply_wm[(size_t)b * 256 + t];
  if (t < 16) Ol[t] = apply_ofs[(size_t)b * 16 + t];
  __syncthreads();

  const v4f* xb = (const v4f*)x + (size_t)b * 16 * 1024;  // 1024 v4f per channel row
  v4f* yb = (v4f*)y + (size_t)b * 16 * 1024;
  const int f = chunk * 256 + t;  // v4f index within channel row

  v4f v[16];
#pragma unroll
  for (int d = 0; d < 16; ++d) v[d] = xb[d * 1024 + f];

#pragma unroll
  for (int cch = 0; cch < 16; ++cch) {
    v4f acc = Ol[cch];
#pragma unroll
    for (int d = 0; d < 16; ++d) acc += Wl[cch * 16 + d] * v[d];
    yb[cch * 1024 + f] = acc;
  }
}

// ---------------------------------------------------------------------------
extern "C" void kernel_launch(void* const* d_in, const int* in_sizes, int n_in,
                              void* d_out, int out_size, void* d_ws, size_t ws_size,
                              hipStream_t stream) {
  const float* x = (const float*)d_in[0];
  const float* swm = (const float*)d_in[1];
  const float* swv = (const float*)d_in[2];
  const float* weight = (const float*)d_in[3];
  const float* bias = (const float*)d_in[4];
  float* out = (float*)d_out;

  float* ws = (float*)d_ws;
  float* part = ws;                            // 1024*152 (2 rows per instance)
  float* awm = part + (size_t)NINST * NST2;    // 512*256
  float* aofs = awm + (size_t)NINST * 256;     // 512*16

  k_inst_stats<<<NINST * 2, 256, 0, stream>>>(x, part);
  k_newton<<<NINST, 256, 0, stream>>>(part, swm, swv, weight, bias, awm, aofs);
  k_apply<<<NINST * 4, 256, 0, stream>>>(x, awm, aofs, out);
}